// Round 3
// 1726.420 us; speedup vs baseline: 6.4853x; 6.4853x over previous
//
#include <hip/hip_runtime.h>
#include <stdint.h>

// Window MHA fused kernel, bf16-MFMA version.
// 4096 windows x (L=49 tokens padded to 64, EMB=384), 12 heads x 32.
// One block per window, 512 threads (8 waves), MFMA 16x16x32 bf16 everywhere.

#define LTOK 49
#define EMB 384
#define NH 12
#define HD 32
#define SCALE 0.17677669529663687f  // 1/sqrt(32)

typedef short bf16x8 __attribute__((ext_vector_type(8)));
typedef float f32x4 __attribute__((ext_vector_type(4)));

// ---- LDS map (bytes) ----
// All bf16 tiles XOR-swizzled at 16B-granule level for conflict-free ds_read_b128.
#define XS_OFF   0        // X bf16 [64][384], rows 768B (rows 49..63 zero)
#define QO_OFF   49152    // Q bf16 [2 heads][64 tok][32 d], rows 64B (pre-scaled)
#define KO_OFF   57344    // K bf16 [2][64][32]
#define VO_OFF   65536    // V^T bf16 [2][32 d][64 tok], rows 128B (pad tokens zero)
#define AL_OFF   73728    // alpha bf16 [8 waves][16 rows][64], rows 128B
#define CTX_OFF  90112    // ctx bf16 [64][384], rows 768B
#define BQ_OFF   139264   // b_qkv f32 [1152]
#define BO_OFF   143872   // b_out f32 [384]
#define SMEM_TOTAL 145408 // <= 163840

// Per-head stride inside QO/KO/VO: 64tok*32d*2B = 32d*128B = 4096 bytes.
// (Round-0 bug: this was 8192, overflowing each buffer into the next.)
#define HSTRIDE 4096

__device__ __forceinline__ unsigned short f2bf(float f) {
    union { float f; unsigned int u; } v; v.f = f;
    return (unsigned short)((v.u + 0x7FFFu + ((v.u >> 16) & 1u)) >> 16);  // RNE
}

// swizzled byte offsets: rows of 768B (48 granules), 64B (4), 128B (8)
__device__ __forceinline__ int swz768(int r, int g) {
    return r * 768 + (((g & ~7) | ((g ^ r) & 7)) << 4);
}
__device__ __forceinline__ int swz64(int r, int g) {
    return r * 64 + (((g ^ (r >> 1)) & 3) << 4);
}
__device__ __forceinline__ int swz128(int r, int g) {
    return r * 128 + (((g ^ r) & 7) << 4);
}

// Setup: pack w_qkv (384x1152) and w_out (384x384) into bf16 B-fragment order
// [ntile][kstep][lane][8], and gather relative-position bias to (12,49,49) f32.
//   wq_frag: 72 ntiles * 12 ksteps * 64 lanes * 8 = 442368 bf16
//   wo_frag: 24 * 12 * 64 * 8 = 147456 bf16
// fragment element: k = ks*32 + (lane>>4)*8 + j, c = nt*16 + (lane&15)
__global__ __launch_bounds__(256) void setup_k(
    const float* __restrict__ wqkv, const float* __restrict__ wout,
    const float* __restrict__ table, const int* __restrict__ relidx,
    short* __restrict__ wq_frag, short* __restrict__ wo_frag,
    float* __restrict__ bias_m)
{
    int idx = blockIdx.x * 256 + threadIdx.x;
    if (idx < 55296) {
        int ln = idx & 63, t = idx >> 6;          // t = nt*12 + ks
        int nt = t / 12, ks = t % 12;
        int c  = nt * 16 + (ln & 15);
        int k0 = ks * 32 + (ln >> 4) * 8;
        short4 p0, p1;
        p0.x = (short)f2bf(wqkv[(k0 + 0) * 1152 + c]);
        p0.y = (short)f2bf(wqkv[(k0 + 1) * 1152 + c]);
        p0.z = (short)f2bf(wqkv[(k0 + 2) * 1152 + c]);
        p0.w = (short)f2bf(wqkv[(k0 + 3) * 1152 + c]);
        p1.x = (short)f2bf(wqkv[(k0 + 4) * 1152 + c]);
        p1.y = (short)f2bf(wqkv[(k0 + 5) * 1152 + c]);
        p1.z = (short)f2bf(wqkv[(k0 + 6) * 1152 + c]);
        p1.w = (short)f2bf(wqkv[(k0 + 7) * 1152 + c]);
        *(short4*)(wq_frag + idx * 8)     = p0;
        *(short4*)(wq_frag + idx * 8 + 4) = p1;
    } else if (idx < 73728) {
        int i2 = idx - 55296;
        int ln = i2 & 63, t = i2 >> 6;
        int nt = t / 12, ks = t % 12;
        int c  = nt * 16 + (ln & 15);
        int k0 = ks * 32 + (ln >> 4) * 8;
        short4 p0, p1;
        p0.x = (short)f2bf(wout[(k0 + 0) * 384 + c]);
        p0.y = (short)f2bf(wout[(k0 + 1) * 384 + c]);
        p0.z = (short)f2bf(wout[(k0 + 2) * 384 + c]);
        p0.w = (short)f2bf(wout[(k0 + 3) * 384 + c]);
        p1.x = (short)f2bf(wout[(k0 + 4) * 384 + c]);
        p1.y = (short)f2bf(wout[(k0 + 5) * 384 + c]);
        p1.z = (short)f2bf(wout[(k0 + 6) * 384 + c]);
        p1.w = (short)f2bf(wout[(k0 + 7) * 384 + c]);
        *(short4*)(wo_frag + i2 * 8)     = p0;
        *(short4*)(wo_frag + i2 * 8 + 4) = p1;
    } else if (idx < 102540) {
        int t = idx - 73728;
        int h = t / 2401, ij = t % 2401;
        bias_m[h * 2401 + ij] = table[relidx[ij] * 12 + h];
    }
}

__global__ __launch_bounds__(512) void wmha_fused(
    const float* __restrict__ x, const float* __restrict__ mask,
    const float* __restrict__ b_qkv, const float* __restrict__ b_out,
    const short* __restrict__ wq_frag, const short* __restrict__ wo_frag,
    const float* __restrict__ bias_m, float* __restrict__ out)
{
    extern __shared__ __align__(16) char smem[];
    const int tid  = threadIdx.x;
    const int lane = tid & 63;
    const int wv   = tid >> 6;       // wave 0..7
    const int l15  = lane & 15;
    const int lg   = lane >> 4;      // lane group 0..3
    const int win  = blockIdx.x;
    const int wi   = win & 63;       // window-in-NW for mask
    const f32x4 z4 = {0.f, 0.f, 0.f, 0.f};

    // ---- Phase 0: stage X (bf16, zero-padded to 64 rows) + biases ----
    {
        const float* xw = x + (size_t)win * (LTOK * EMB);
        #pragma unroll 1
        for (int i = tid; i < (64 * EMB) / 4; i += 512) {
            int e = i << 2;
            int r = e / EMB, c = e % EMB;
            float4 v = make_float4(0.f, 0.f, 0.f, 0.f);
            if (r < LTOK) v = *(const float4*)(xw + e);
            short4 p;
            p.x = (short)f2bf(v.x); p.y = (short)f2bf(v.y);
            p.z = (short)f2bf(v.z); p.w = (short)f2bf(v.w);
            *(short4*)(smem + XS_OFF + swz768(r, c >> 3) + (c & 7) * 2) = p;
        }
        for (int i = tid; i < 3 * EMB; i += 512)
            ((float*)(smem + BQ_OFF))[i] = b_qkv[i];
        if (tid < EMB)
            ((float*)(smem + BO_OFF))[tid] = b_out[tid];
    }
    __syncthreads();

    const int mtq  = wv & 3;          // M-tile for GEMM phases
    const int ntg  = wv >> 2;         // N-strip half
    const int arow = mtq * 16 + l15;  // A-fragment row

    // ---- 6 head-pair groups ----
    for (int grp = 0; grp < 6; ++grp) {
        const int h0 = grp * 2;

        // -- QKV partial GEMM: this group's 192 columns (2 heads x {q,k,v}) --
        f32x4 acc[6];
        int boff[6], wch[6], whh[6], wdd[6];
        #pragma unroll
        for (int u = 0; u < 6; ++u) {
            acc[u] = z4;
            int lnt = ntg * 6 + u;                    // local ntile 0..11
            int which = lnt >> 2, hh = (lnt >> 1) & 1, t = lnt & 1;
            int gnt = which * 24 + (h0 + hh) * 2 + t; // global ntile 0..71
            boff[u] = gnt * 6144 + lane * 8;          // bf16-element offset (ks=0)
            wch[u] = which; whh[u] = hh; wdd[u] = t * 16 + l15;
        }
        bf16x8 a_cur = *(const bf16x8*)(smem + XS_OFF + swz768(arow, lg));
        bf16x8 b_cur[6];
        #pragma unroll
        for (int u = 0; u < 6; ++u)
            b_cur[u] = *(const bf16x8*)(wq_frag + boff[u]);
        #pragma unroll 2
        for (int ks = 0; ks < 11; ++ks) {
            bf16x8 a_nx = *(const bf16x8*)(smem + XS_OFF + swz768(arow, (ks + 1) * 4 + lg));
            bf16x8 b_nx[6];
            #pragma unroll
            for (int u = 0; u < 6; ++u)
                b_nx[u] = *(const bf16x8*)(wq_frag + boff[u] + (ks + 1) * 512);
            #pragma unroll
            for (int u = 0; u < 6; ++u)
                acc[u] = __builtin_amdgcn_mfma_f32_16x16x32_bf16(a_cur, b_cur[u], acc[u], 0, 0, 0);
            a_cur = a_nx;
            #pragma unroll
            for (int u = 0; u < 6; ++u) b_cur[u] = b_nx[u];
        }
        #pragma unroll
        for (int u = 0; u < 6; ++u)
            acc[u] = __builtin_amdgcn_mfma_f32_16x16x32_bf16(a_cur, b_cur[u], acc[u], 0, 0, 0);

        // write Q (pre-scaled) / K token-major, V transposed (pad tokens zeroed)
        {
            const float* BQ = (const float*)(smem + BQ_OFF);
            const int tk0 = mtq * 16 + lg * 4;
            #pragma unroll
            for (int u = 0; u < 6; ++u) {
                int d = wdd[u];
                float bias = BQ[wch[u] * EMB + (h0 + whh[u]) * HD + d];
                if (wch[u] == 0) {
                    #pragma unroll
                    for (int q = 0; q < 4; ++q)
                        *(unsigned short*)(smem + QO_OFF + whh[u] * HSTRIDE +
                                           swz64(tk0 + q, d >> 3) + (d & 7) * 2)
                            = f2bf((acc[u][q] + bias) * SCALE);
                } else if (wch[u] == 1) {
                    #pragma unroll
                    for (int q = 0; q < 4; ++q)
                        *(unsigned short*)(smem + KO_OFF + whh[u] * HSTRIDE +
                                           swz64(tk0 + q, d >> 3) + (d & 7) * 2)
                            = f2bf(acc[u][q] + bias);
                } else {
                    float v0 = (tk0 + 0 < LTOK) ? acc[u][0] + bias : 0.f;
                    float v1 = (tk0 + 1 < LTOK) ? acc[u][1] + bias : 0.f;
                    float v2 = (tk0 + 2 < LTOK) ? acc[u][2] + bias : 0.f;
                    float v3 = (tk0 + 3 < LTOK) ? acc[u][3] + bias : 0.f;
                    short4 p;
                    p.x = (short)f2bf(v0); p.y = (short)f2bf(v1);
                    p.z = (short)f2bf(v2); p.w = (short)f2bf(v3);
                    *(short4*)(smem + VO_OFF + whh[u] * HSTRIDE +
                               swz128(d, tk0 >> 3) + (tk0 & 7) * 2) = p;
                }
            }
        }
        __syncthreads();

        // -- attention: wave -> (head hh, M-tile amt); softmax lives in registers --
        {
            const int hh  = wv >> 2;
            const int amt = wv & 3;
            const int h   = h0 + hh;
            bf16x8 aq = *(const bf16x8*)(smem + QO_OFF + hh * HSTRIDE +
                                         swz64(amt * 16 + l15, lg));
            f32x4 s[4];
            #pragma unroll
            for (int nt = 0; nt < 4; ++nt) {
                bf16x8 bk = *(const bf16x8*)(smem + KO_OFF + hh * HSTRIDE +
                                             swz64(nt * 16 + l15, lg));
                s[nt] = __builtin_amdgcn_mfma_f32_16x16x32_bf16(aq, bk, z4, 0, 0, 0);
            }
            const int rl0 = lg * 4;  // C-frag local row base
            #pragma unroll
            for (int nt = 0; nt < 4; ++nt) {
                int j = nt * 16 + l15;
                #pragma unroll
                for (int q = 0; q < 4; ++q) {
                    int i = amt * 16 + rl0 + q;
                    float sv = s[nt][q];
                    if (j < LTOK) {
                        if (i < LTOK) {
                            int ij = i * 49 + j;
                            sv += bias_m[h * 2401 + ij] + mask[wi * 2401 + ij];
                        }
                    } else sv = -1e30f;  // pad cols -> exp underflows to 0
                    s[nt][q] = sv;
                }
            }
            // row-wise softmax: row lives in one 16-lane group (4 rows/lane)
            float m4[4];
            #pragma unroll
            for (int q = 0; q < 4; ++q)
                m4[q] = fmaxf(fmaxf(s[0][q], s[1][q]), fmaxf(s[2][q], s[3][q]));
            #pragma unroll
            for (int off = 1; off <= 8; off <<= 1) {
                #pragma unroll
                for (int q = 0; q < 4; ++q)
                    m4[q] = fmaxf(m4[q], __shfl_xor(m4[q], off));
            }
            float sum4[4] = {0.f, 0.f, 0.f, 0.f};
            #pragma unroll
            for (int nt = 0; nt < 4; ++nt) {
                #pragma unroll
                for (int q = 0; q < 4; ++q) {
                    float e = __expf(s[nt][q] - m4[q]);
                    s[nt][q] = e;
                    sum4[q] += e;
                }
            }
            #pragma unroll
            for (int off = 1; off <= 8; off <<= 1) {
                #pragma unroll
                for (int q = 0; q < 4; ++q)
                    sum4[q] += __shfl_xor(sum4[q], off);
            }
            float inv4[4];
            #pragma unroll
            for (int q = 0; q < 4; ++q) inv4[q] = 1.f / sum4[q];

            // write unnormalized alpha (bf16) into this wave's private buffer
            #pragma unroll
            for (int nt = 0; nt < 4; ++nt) {
                int j = nt * 16 + l15;
                #pragma unroll
                for (int q = 0; q < 4; ++q)
                    *(unsigned short*)(smem + AL_OFF + wv * 2048 +
                                       swz128(rl0 + q, j >> 3) + (j & 7) * 2)
                        = f2bf(s[nt][q]);
            }
            // A @ V (K-dim = 64 tokens, 2 ksteps), normalize at C-frag in f32
            #pragma unroll
            for (int dt = 0; dt < 2; ++dt) {
                f32x4 c = z4;
                #pragma unroll
                for (int k2 = 0; k2 < 2; ++k2) {
                    bf16x8 aa = *(const bf16x8*)(smem + AL_OFF + wv * 2048 +
                                                 swz128(l15, lg + k2 * 4));
                    bf16x8 bv = *(const bf16x8*)(smem + VO_OFF + hh * HSTRIDE +
                                                 swz128(dt * 16 + l15, lg + k2 * 4));
                    c = __builtin_amdgcn_mfma_f32_16x16x32_bf16(aa, bv, c, 0, 0, 0);
                }
                int ec = h * HD + dt * 16 + l15;
                #pragma unroll
                for (int q = 0; q < 4; ++q) {
                    int tok = amt * 16 + rl0 + q;
                    *(unsigned short*)(smem + CTX_OFF + swz768(tok, ec >> 3) + (ec & 7) * 2)
                        = f2bf(c[q] * inv4[q]);
                }
            }
        }
        __syncthreads();
    }

    // ---- Phase 3: out = ctx(64x384) @ w_out(384x384) + b_out ----
    {
        const float* BO = (const float*)(smem + BO_OFF);
        const int tk0 = mtq * 16 + lg * 4;
        #pragma unroll 1
        for (int pass = 0; pass < 2; ++pass) {
            const int nt0 = ntg * 12 + pass * 6;
            f32x4 acc[6];
            #pragma unroll
            for (int u = 0; u < 6; ++u) acc[u] = z4;
            bf16x8 a_cur = *(const bf16x8*)(smem + CTX_OFF + swz768(arow, lg));
            bf16x8 b_cur[6];
            #pragma unroll
            for (int u = 0; u < 6; ++u)
                b_cur[u] = *(const bf16x8*)(wo_frag + ((nt0 + u) * 768 + lane) * 8);
            #pragma unroll 2
            for (int ks = 0; ks < 11; ++ks) {
                bf16x8 a_nx = *(const bf16x8*)(smem + CTX_OFF + swz768(arow, (ks + 1) * 4 + lg));
                bf16x8 b_nx[6];
                #pragma unroll
                for (int u = 0; u < 6; ++u)
                    b_nx[u] = *(const bf16x8*)(wo_frag + ((nt0 + u) * 768 + lane) * 8 + (ks + 1) * 512);
                #pragma unroll
                for (int u = 0; u < 6; ++u)
                    acc[u] = __builtin_amdgcn_mfma_f32_16x16x32_bf16(a_cur, b_cur[u], acc[u], 0, 0, 0);
                a_cur = a_nx;
                #pragma unroll
                for (int u = 0; u < 6; ++u) b_cur[u] = b_nx[u];
            }
            #pragma unroll
            for (int u = 0; u < 6; ++u)
                acc[u] = __builtin_amdgcn_mfma_f32_16x16x32_bf16(a_cur, b_cur[u], acc[u], 0, 0, 0);
            #pragma unroll
            for (int u = 0; u < 6; ++u) {
                int col = (nt0 + u) * 16 + l15;
                float bo = BO[col];
                #pragma unroll
                for (int q = 0; q < 4; ++q) {
                    int tok = tk0 + q;
                    if (tok < LTOK)
                        out[((size_t)win * LTOK + tok) * EMB + col] = acc[u][q] + bo;
                }
            }
        }
    }
}

extern "C" void kernel_launch(void* const* d_in, const int* in_sizes, int n_in,
                              void* d_out, int out_size, void* d_ws, size_t ws_size,
                              hipStream_t stream)
{
    const float* x      = (const float*)d_in[0];
    const float* mask   = (const float*)d_in[1];
    const float* w_qkv  = (const float*)d_in[2];
    const float* b_qkv  = (const float*)d_in[3];
    const float* w_out  = (const float*)d_in[4];
    const float* b_out  = (const float*)d_in[5];
    const float* table  = (const float*)d_in[6];
    const int*   relidx = (const int*)d_in[7];
    float* out = (float*)d_out;

    short* wq_frag = (short*)d_ws;                      // 442368 bf16 = 884736 B
    short* wo_frag = wq_frag + 442368;                  // 147456 bf16 = 294912 B
    float* bias_m  = (float*)((char*)d_ws + 1179648);   // 12*2401 f32 = 115248 B
    size_t need = 1179648 + 115248;
    if (ws_size < need) return;

    setup_k<<<401, 256, 0, stream>>>(w_qkv, w_out, table, relidx,
                                     wq_frag, wo_frag, bias_m);

    // >64KB dynamic LDS opt-in (idempotent; graph-capture safe)
    hipFuncSetAttribute(reinterpret_cast<const void*>(wmha_fused),
                        hipFuncAttributeMaxDynamicSharedMemorySize, SMEM_TOTAL);
    wmha_fused<<<4096, 512, SMEM_TOTAL, stream>>>(x, mask, b_qkv, b_out,
                                                  wq_frag, wo_frag, bias_m, out);
}